// Round 6
// baseline (260.851 us; speedup 1.0000x reference)
//
#include <hip/hip_runtime.h>
#include <cstdint>

// Fisher-Kolmogorov explicit Euler, B=2, 128^3, up to 40 masked micro-steps.
// Round-6: 2-step fusion with FULL LDS staging. Phase 0 loads the u region
// (8z x 12y x 128x) into LDS once per element (coalesced, zero-padded halo);
// phase 1 computes step-1 (6x10x128) reading all 7 u-neighbors from LDS into
// an LDS s1 buffer; phase 2 computes step-2 on the 4x8x128 interior. This
// cuts per-block vector-memory bytes ~2.1x (u: 150KB->48KB), the round-5
// binder. LDS 78KB -> 2 blocks/CU; 512 blocks per item-pair = one full round.

constexpr int NX = 128, NY = 128, NZ = 128;
constexpr int PLANE = NX * NY;            // 16384
constexpr int VOL   = NZ * PLANE;         // 2,097,152
constexpr int TOTAL = 2 * VOL;            // 4,194,304
constexpr float DT  = 0.1f;               // MICRO_DT
constexpr int MAX_PAIRS = 20;             // 40 micro-steps / 2

constexpr int TY = 8, TZ = 4;             // block interior tile (x is full 128)
constexpr int RY = TY + 2, RZ = TZ + 2;   // step-1 region: 10 y x 6 z
constexpr int UY = TY + 4, UZ = TZ + 4;   // staged u region: 12 y x 8 z
constexpr int REGION_F4  = RZ * RY * 32;  // 1920
constexpr int UREGION_F4 = UZ * UY * 32;  // 3072 (= 12 f4 loads/thread)
constexpr int BLOCKS = 2 * (NZ / TZ) * (NY / TY);  // 1024

__device__ __forceinline__ float4 ld4(const float* p) { return *(const float4*)p; }

__device__ __forceinline__ uint32_t f2bf(float f) {
    uint32_t u = __float_as_uint(f);
    u += 0x7fffu + ((u >> 16) & 1u);      // round-to-nearest-even
    return u >> 16;
}
__device__ __forceinline__ float bf_lo(uint32_t p) { return __uint_as_float(p << 16); }
__device__ __forceinline__ float bf_hi(uint32_t p) { return __uint_as_float(p & 0xffff0000u); }
__device__ __forceinline__ float clip01(float v) { return fminf(fmaxf(v, 0.0f), 1.0f); }

__device__ __forceinline__ float4 fkstep(float4 c, float xm, float xp,
                                         float4 ym, float4 yp,
                                         float4 zm, float4 zp,
                                         float4 Dv, float4 Rv) {
    float4 o;
    o.x = fmaf(DT, fmaf(Dv.x, (xm + c.y) + (ym.x + yp.x) + (zm.x + zp.x) - 6.0f * c.x,
                        Rv.x * c.x * (1.0f - c.x)), c.x);
    o.y = fmaf(DT, fmaf(Dv.y, (c.x + c.z) + (ym.y + yp.y) + (zm.y + zp.y) - 6.0f * c.y,
                        Rv.y * c.y * (1.0f - c.y)), c.y);
    o.z = fmaf(DT, fmaf(Dv.z, (c.y + c.w) + (ym.z + yp.z) + (zm.z + zp.z) - 6.0f * c.z,
                        Rv.z * c.z * (1.0f - c.z)), c.z);
    o.w = fmaf(DT, fmaf(Dv.w, (c.z + xp) + (ym.w + yp.w) + (zm.w + zp.w) - 6.0f * c.w,
                        Rv.w * c.w * (1.0f - c.w)), c.w);
    return o;
}

__global__ __launch_bounds__(256, 2)
void fk_pair(const float* __restrict__ src, float* __restrict__ dst0,
             float* __restrict__ out, const float* __restrict__ u0,
             const float* __restrict__ Dm, const float* __restrict__ Rm,
             uint32_t* __restrict__ dr, const int* __restrict__ dtd, int p)
{
    const int b  = blockIdx.x >> 9;                  // batch item (block-uniform)
    int d = dtd[b]; d = d < 0 ? 0 : (d > 4 ? 4 : d);
    const int steps = d * 10;

    const int zb = (blockIdx.x >> 4) & 31;
    const int yt = blockIdx.x & 15;
    const int z0 = zb * TZ, y0 = yt * TY;
    const int tid = threadIdx.x;
    const int xq  = tid & 31;                        // float4 lane within row
    const int yi  = tid >> 5;                        // 0..7
    const int baseb = b << 21;
    const float4 zero = make_float4(0.f, 0.f, 0.f, 0.f);

    if (2 * p >= steps) {
        // d==0 items never get a step write: emit clip(u0) once, in pair 0.
        if (steps == 0 && p == 0) {
            #pragma unroll
            for (int k = 0; k < TZ; ++k) {
                const int idx = baseb + (z0 + k) * PLANE + (y0 + yi) * NX + (xq << 2);
                const float4 v = ld4(u0 + idx);
                float4 o;
                o.x = clip01(v.x); o.y = clip01(v.y);
                o.z = clip01(v.z); o.w = clip01(v.w);
                *(float4*)(out + idx) = o;
            }
        }
        return;                                      // block-uniform exit
    }
    const bool first = (p == 0);
    const bool last  = (2 * p == steps - 2);
    float* __restrict__ dst = last ? out : dst0;

    __shared__ float su[UZ * UY * NX];               // 48 KiB staged u region
    __shared__ float s1[RZ * RY * NX];               // 30 KiB step-1 region

    // ---- Phase 0: stage u region into LDS, each element once, coalesced ----
    #pragma unroll
    for (int it = 0; it < UREGION_F4 / 256; ++it) {  // 12
        const int i = tid + it * 256;
        const int cxq = i & 31;
        const int r   = i >> 5;                      // 0..95: uz*UY + uy
        const int uy  = r % UY;
        const int uz  = r / UY;
        const int y = y0 - 2 + uy;
        const int z = z0 - 2 + uz;
        float4 v = zero;                             // Dirichlet zero halo
        if ((unsigned)y < (unsigned)NY && (unsigned)z < (unsigned)NZ)
            v = ld4(src + baseb + z * PLANE + y * NX + (cxq << 2));
        *(float4*)&su[r * NX + (cxq << 2)] = v;
    }
    __syncthreads();

    // ---- Phase 1: step-1 on the +1-halo region, u from LDS, into LDS ----
    #pragma unroll
    for (int it = 0; it < 8; ++it) {
        const int i = tid + it * 256;
        if (i >= REGION_F4) break;                   // last iter: 128 lanes idle
        const int cxq = i & 31;
        const int t2  = i >> 5;                      // rz*RY + ry
        const int ry  = t2 % RY;
        const int rz  = t2 / RY;
        const int y = y0 - 1 + ry;
        const int z = z0 - 1 + rz;
        float4 o = zero;                             // out-of-domain -> 0
        if ((unsigned)y < (unsigned)NY && (unsigned)z < (unsigned)NZ) {
            const float* uc = &su[((rz + 1) * UY + (ry + 1)) * NX];
            const float4 c  = *(const float4*)&uc[cxq << 2];
            const float xm  = (cxq > 0)  ? ((const float4*)&uc[(cxq - 1) << 2])->w : 0.0f;
            const float xp  = (cxq < 31) ? ((const float4*)&uc[(cxq + 1) << 2])->x : 0.0f;
            const float4 ym4 = *(const float4*)&su[((rz + 1) * UY + ry) * NX + (cxq << 2)];
            const float4 yp4 = *(const float4*)&su[((rz + 1) * UY + ry + 2) * NX + (cxq << 2)];
            const float4 zm4 = *(const float4*)&su[(rz * UY + ry + 1) * NX + (cxq << 2)];
            const float4 zp4 = *(const float4*)&su[((rz + 2) * UY + ry + 1) * NX + (cxq << 2)];
            const int idx = baseb + z * PLANE + y * NX + (cxq << 2);
            float4 Dv, Rv;
            if (first) {
                Dv = ld4(Dm + idx);
                Rv = ld4(Rm + idx);
            } else {
                const uint4 pr = *(const uint4*)(dr + idx);
                Dv.x = bf_lo(pr.x); Dv.y = bf_lo(pr.y); Dv.z = bf_lo(pr.z); Dv.w = bf_lo(pr.w);
                Rv.x = bf_hi(pr.x); Rv.y = bf_hi(pr.y); Rv.z = bf_hi(pr.z); Rv.w = bf_hi(pr.w);
            }
            o = fkstep(c, xm, xp, ym4, yp4, zm4, zp4, Dv, Rv);
        }
        *(float4*)&s1[t2 * NX + (cxq << 2)] = o;
    }
    __syncthreads();

    // ---- Phase 2: step-2 on the interior from LDS s1 ----
    const int ry = yi + 1;
    const int y  = y0 + yi;
    #pragma unroll
    for (int k = 0; k < TZ; ++k) {
        const int rz = k + 1;
        const float* rowc = &s1[(rz * RY + ry) * NX];
        const float4 c = *(const float4*)&rowc[xq << 2];
        float xm = 0.0f, xp = 0.0f;
        if (xq > 0)  xm = ((const float4*)&rowc[(xq - 1) << 2])->w;
        if (xq < 31) xp = ((const float4*)&rowc[(xq + 1) << 2])->x;
        const float4 ym4 = *(const float4*)&s1[(rz * RY + ry - 1) * NX + (xq << 2)];
        const float4 yp4 = *(const float4*)&s1[(rz * RY + ry + 1) * NX + (xq << 2)];
        const float4 zm4 = *(const float4*)&s1[((rz - 1) * RY + ry) * NX + (xq << 2)];
        const float4 zp4 = *(const float4*)&s1[((rz + 1) * RY + ry) * NX + (xq << 2)];

        const int idx = baseb + (z0 + k) * PLANE + y * NX + (xq << 2);
        float4 Dv, Rv;
        if (first) {
            Dv = ld4(Dm + idx);
            Rv = ld4(Rm + idx);
            uint4 pk;                                // emit packed dr for pairs >= 1
            pk.x = f2bf(Dv.x) | (f2bf(Rv.x) << 16);
            pk.y = f2bf(Dv.y) | (f2bf(Rv.y) << 16);
            pk.z = f2bf(Dv.z) | (f2bf(Rv.z) << 16);
            pk.w = f2bf(Dv.w) | (f2bf(Rv.w) << 16);
            *(uint4*)(dr + idx) = pk;
        } else {
            const uint4 pr = *(const uint4*)(dr + idx);
            Dv.x = bf_lo(pr.x); Dv.y = bf_lo(pr.y); Dv.z = bf_lo(pr.z); Dv.w = bf_lo(pr.w);
            Rv.x = bf_hi(pr.x); Rv.y = bf_hi(pr.y); Rv.z = bf_hi(pr.z); Rv.w = bf_hi(pr.w);
        }
        float4 o = fkstep(c, xm, xp, ym4, yp4, zm4, zp4, Dv, Rv);
        if (last) {
            o.x = clip01(o.x); o.y = clip01(o.y);
            o.z = clip01(o.z); o.w = clip01(o.w);
        }
        *(float4*)(dst + idx) = o;
    }
}

extern "C" void kernel_launch(void* const* d_in, const int* in_sizes, int n_in,
                              void* d_out, int out_size, void* d_ws, size_t ws_size,
                              hipStream_t stream) {
    const float* u0  = (const float*)d_in[0];
    const float* Dm  = (const float*)d_in[1];
    const float* Rm  = (const float*)d_in[2];
    const int*   dtd = (const int*)d_in[3];
    float* out = (float*)d_out;
    float* ws  = (float*)d_ws;
    // ws layout: [0,16M) buf0, [16M,32M) buf1, [32M,48M) packed DR (ws=256MB).
    float* buf[2] = { ws, ws + TOTAL };
    uint32_t* dr = (uint32_t*)(ws + 2 * TOTAL);

    // Pair p advances steps 2p,2p+1. src: u0 for p=0 else buf[(p-1)&1];
    // normal dst alternates buf[p&1]; an item's LAST pair redirects to `out`
    // (clipped) on-device. d==0 items emit clip(u0) during pair 0.
    for (int p = 0; p < MAX_PAIRS; ++p) {
        const float* src = (p == 0) ? u0 : buf[(p - 1) & 1];
        fk_pair<<<BLOCKS, 256, 0, stream>>>(src, buf[p & 1], out, u0,
                                            Dm, Rm, dr, dtd, p);
    }
}